// Round 10
// baseline (169.330 us; speedup 1.0000x reference)
//
#include <hip/hip_runtime.h>
#include <math.h>

#define NN 50000
#define NE 800000
#define DD 64
#define FC_BLOCKS 782  // ceil(NN/64)
#define N4 12503       // ints of deg (NN+12) zeroed as int4
#define ZB 49          // ceil(N4/256) zero blocks appended to fc1 grid

typedef __attribute__((ext_vector_type(8))) short short8v;
typedef __attribute__((ext_vector_type(4))) float floatx4;

__device__ __forceinline__ unsigned bf16r(float x) {  // round-to-nearest-even bf16
  unsigned u = __float_as_uint(x);
  return (u + 0x7fffu + ((u >> 16) & 1u)) >> 16;
}

// -------------------- kernels --------------------

// histogram dst degrees, 4 edges/thread, capturing per-edge position
__global__ void k_hist(const int4* __restrict__ dst4, int* __restrict__ deg,
                       int4* __restrict__ pos4) {
  int q = blockIdx.x * 256 + threadIdx.x;
  if (q >= NE / 4) return;
  int4 dn = dst4[q];
  int4 p;
  p.x = atomicAdd(&deg[dn.x], 1);
  p.y = atomicAdd(&deg[dn.y], 1);
  p.z = atomicAdd(&deg[dn.z], 1);
  p.w = atomicAdd(&deg[dn.w], 1);
  pos4[q] = p;
}

// single-kernel exclusive scan: each block redundantly pre-reduces its base
// (sum deg[0..blockStart), <=48 ints/thread), then local shuffle-scan.
__global__ void k_scan(const int* __restrict__ deg, int* __restrict__ rp) {
  __shared__ int wred[16];
  __shared__ int woff[16];
  __shared__ int sbase;
  int t = threadIdx.x;
  int lane = t & 63, w = t >> 6;
  int blockStart = blockIdx.x << 10;
  // block base offset
  int acc = 0;
  for (int i = t; i < blockStart; i += 1024) acc += deg[i];
#pragma unroll
  for (int off = 32; off > 0; off >>= 1) acc += __shfl_xor(acc, off, 64);
  if (lane == 0) wred[w] = acc;
  __syncthreads();
  if (t == 0) {
    int b = 0;
#pragma unroll
    for (int k = 0; k < 16; ++k) b += wred[k];
    sbase = b;
  }
  // local scan
  int i = blockStart + t;
  int v = (i < NN) ? deg[i] : 0;
  int sc = v;  // inclusive within wave
#pragma unroll
  for (int off = 1; off < 64; off <<= 1) {
    int x = __shfl_up(sc, off, 64);
    if (lane >= off) sc += x;
  }
  if (lane == 63) woff[w] = sc;
  __syncthreads();
  if (t < 16) {
    int ws = woff[t];
    int s2 = ws;
#pragma unroll
    for (int off = 1; off < 16; off <<= 1) {
      int x = __shfl_up(s2, off, 64);
      if (t >= off) s2 += x;
    }
    woff[t] = s2 - ws;  // exclusive wave offset
  }
  __syncthreads();
  if (i <= NN) rp[i] = sc - v + woff[w] + sbase;  // rp[NN] lands as NE
}

// atomic-free scatter, 4 edges/thread
__global__ void k_scatter(const int4* __restrict__ src4, const int4* __restrict__ dst4,
                          const int* __restrict__ rp, const int4* __restrict__ pos4,
                          int* __restrict__ ssrc) {
  int q = blockIdx.x * 256 + threadIdx.x;
  if (q >= NE / 4) return;
  int4 s = src4[q], dn = dst4[q], p = pos4[q];
  ssrc[rp[dn.x] + p.x] = s.x;
  ssrc[rp[dn.y] + p.y] = s.y;
  ssrc[rp[dn.z] + p.z] = s.z;
  ssrc[rp[dn.w] + p.w] = s.w;
}

// MFMA FC (+ optional deg-zero blocks appended to the grid for layer 1)
__global__ void __launch_bounds__(256) k_fc_mfma(const float* __restrict__ h,
                                                 const int* __restrict__ ids,
                                                 const float* __restrict__ W,
                                                 const float* __restrict__ b,
                                                 unsigned* __restrict__ hfb,
                                                 int4* __restrict__ zbuf, int n4) {
  if (blockIdx.x >= FC_BLOCKS) {  // zero-deg tail blocks (layer 1 only)
    int i = (blockIdx.x - FC_BLOCKS) * 256 + threadIdx.x;
    if (i < n4) zbuf[i] = make_int4(0, 0, 0, 0);
    return;
  }
  int lane = threadIdx.x & 63;
  int wid = threadIdx.x >> 6;
  int nbase = blockIdx.x * 64 + wid * 16;
  if (nbase >= NN) return;
  int r16 = lane & 15, kg = lane >> 4;

  int rowA = ids ? ids[nbase + r16] : (nbase + r16);
  const float* hrow = h + (size_t)rowA * DD;
  short8v afr[2];
#pragma unroll
  for (int kt = 0; kt < 2; ++kt) {
    int k0 = kt * 32 + kg * 8;
#pragma unroll
    for (int i = 0; i < 8; ++i) afr[kt][i] = (short)bf16r(hrow[k0 + i]);
  }
  int orow[4];
#pragma unroll
  for (int r = 0; r < 4; ++r) {
    int node = nbase + kg * 4 + r;
    orow[r] = ids ? ids[node] : node;
  }
  short8v bfr[4][2];
#pragma unroll
  for (int dt = 0; dt < 4; ++dt) {
    const float* wrow = W + (dt * 16 + r16) * 64;
#pragma unroll
    for (int kt = 0; kt < 2; ++kt) {
      int k0 = kt * 32 + kg * 8;
#pragma unroll
      for (int i = 0; i < 8; ++i) bfr[dt][kt][i] = (short)bf16r(wrow[k0 + i]);
    }
  }
#pragma unroll
  for (int dt = 0; dt < 4; ++dt) {
    floatx4 acc = {0.f, 0.f, 0.f, 0.f};
    acc = __builtin_amdgcn_mfma_f32_16x16x32_bf16(afr[0], bfr[dt][0], acc, 0, 0, 0);
    acc = __builtin_amdgcn_mfma_f32_16x16x32_bf16(afr[1], bfr[dt][1], acc, 0, 0, 0);
    int d = dt * 16 + r16;
    float bias = b[d];
#pragma unroll
    for (int r = 0; r < 4; ++r) {
      int node = nbase + kg * 4 + r;
      float feat = fmaxf(acc[r] + bias, 0.f);
      float hv = h[(size_t)orow[r] * DD + d];
      hfb[node * DD + d] = bf16r(hv) | (bf16r(feat) << 16);
    }
  }
}

// One wave per dst node; paired-edge layout: lanes 0-31 process even edges,
// lanes 32-63 odd edges; each lane covers channel pair (2c, 2c+1) via one
// uint2 load -> one load instruction per TWO edges. Wave-uniform work on
// SALU (readfirstlane), dup-slots corrected per half, halves combined with
// shfl_xor(32). Softmax w/o max-subtraction (|e| bounded).
template <bool FINAL>
__global__ void __launch_bounds__(256)
k_edge_t(const unsigned* __restrict__ hfb, const float* __restrict__ h,
         const int* __restrict__ ids, const int* __restrict__ rp,
         const int* __restrict__ ssrc, float* __restrict__ outp, int ostride,
         const float* __restrict__ emb, const int* __restrict__ fids,
         const float* __restrict__ h1) {
  int lane = threadIdx.x & 63;
  int half = lane >> 5;  // 0: even-offset edges, 1: odd-offset edges
  int c = lane & 31;     // channels 2c, 2c+1
  int node = __builtin_amdgcn_readfirstlane(blockIdx.x * 4 + (threadIdx.x >> 6));
  int beg = __builtin_amdgcn_readfirstlane(rp[node]);
  int end = __builtin_amdgcn_readfirstlane(rp[node + 1]);
  int hrow = ids ? __builtin_amdgcn_readfirstlane(ids[node]) : node;
  float2 hdv = *(const float2*)(h + (size_t)hrow * DD + 2 * c);
  float hd0 = hdv.x * 1.44269504f;  // fold log2e: exp(x)=exp2(x*log2e)
  float hd1 = hdv.y * 1.44269504f;
  int lim = end - 1;
  float sA[8] = {0.f, 0.f, 0.f, 0.f, 0.f, 0.f, 0.f, 0.f};
  float aA[8] = {0.f, 0.f, 0.f, 0.f, 0.f, 0.f, 0.f, 0.f};
  float sB[8] = {0.f, 0.f, 0.f, 0.f, 0.f, 0.f, 0.f, 0.f};
  float aB[8] = {0.f, 0.f, 0.f, 0.f, 0.f, 0.f, 0.f, 0.f};
  for (int p = beg; p < end; p += 16) {
    uint2 v[8];
#pragma unroll
    for (int j = 0; j < 8; ++j) {
      int q0 = p + 2 * j;
      q0 = (q0 > lim) ? lim : q0;  // SALU clamp; dups corrected after loop
      int q1 = p + 2 * j + 1;
      q1 = (q1 > lim) ? lim : q1;
      int s0 = __builtin_amdgcn_readfirstlane(ssrc[q0]);
      int s1 = __builtin_amdgcn_readfirstlane(ssrc[q1]);
      int sq = half ? s1 : s0;  // one v_cndmask
      v[j] = *(const uint2*)(hfb + (size_t)sq * DD + 2 * c);
    }
#pragma unroll
    for (int j = 0; j < 8; ++j) {
      float hv0 = __uint_as_float(v[j].x << 16);
      float fv0 = __uint_as_float(v[j].x & 0xffff0000u);
      float hv1 = __uint_as_float(v[j].y << 16);
      float fv1 = __uint_as_float(v[j].y & 0xffff0000u);
      float e0 = __builtin_amdgcn_exp2f(hv0 * hd0);
      float e1 = __builtin_amdgcn_exp2f(hv1 * hd1);
      sA[j] += e0;
      aA[j] = fmaf(fv0, e0, aA[j]);
      sB[j] += e1;
      aB[j] = fmaf(fv1, e1, aB[j]);
    }
  }
  float ss0 = ((sA[0] + sA[1]) + (sA[2] + sA[3])) + ((sA[4] + sA[5]) + (sA[6] + sA[7]));
  float aa0 = ((aA[0] + aA[1]) + (aA[2] + aA[3])) + ((aA[4] + aA[5]) + (aA[6] + aA[7]));
  float ss1 = ((sB[0] + sB[1]) + (sB[2] + sB[3])) + ((sB[4] + sB[5]) + (sB[6] + sB[7]));
  float aa1 = ((aB[0] + aB[1]) + (aB[2] + aB[3])) + ((aB[4] + aB[5]) + (aB[6] + aB[7]));
  int deg = end - beg;
  if (deg > 0) {
    int rem = deg & 15;
    if (rem) {  // uniform branch: clamped duplicate slots exist
      // dup counts per half: offsets rem..15 of the last batch were clamped
      int dups0 = (rem & 1) ? (16 - rem) >> 1 : (17 - rem) >> 1;  // even offsets
      int dups1 = (16 - rem) - dups0;                             // odd offsets
      float fd = (float)(half ? dups1 : dups0);
      int sL = __builtin_amdgcn_readfirstlane(ssrc[lim]);
      uint2 vL = *(const uint2*)(hfb + (size_t)sL * DD + 2 * c);
      float hvL0 = __uint_as_float(vL.x << 16);
      float fvL0 = __uint_as_float(vL.x & 0xffff0000u);
      float hvL1 = __uint_as_float(vL.y << 16);
      float fvL1 = __uint_as_float(vL.y & 0xffff0000u);
      float eL0 = __builtin_amdgcn_exp2f(hvL0 * hd0);
      float eL1 = __builtin_amdgcn_exp2f(hvL1 * hd1);
      ss0 = fmaf(-fd, eL0, ss0);
      aa0 = fmaf(-fd * fvL0, eL0, aa0);
      ss1 = fmaf(-fd, eL1, ss1);
      aa1 = fmaf(-fd * fvL1, eL1, aa1);
    }
    // combine the two edge-halves (disjoint edge sets, same channels)
    ss0 += __shfl_xor(ss0, 32, 64);
    aa0 += __shfl_xor(aa0, 32, 64);
    ss1 += __shfl_xor(ss1, 32, 64);
    aa1 += __shfl_xor(aa1, 32, 64);
  }
  float hv0 = (deg > 0) ? aa0 / ss0 : 0.f;
  float hv1 = (deg > 0) ? aa1 / ss1 : 0.f;
  if (!FINAL) {
    if (half == 0)
      *(float2*)(outp + (size_t)node * ostride + 2 * c) = make_float2(hv0, hv1);
  } else {
    float2 v1 = *(const float2*)(h1 + (size_t)node * DD + 2 * c);
    float ps1 = v1.x * v1.x + v1.y * v1.y;
    float ps2 = hv0 * hv0 + hv1 * hv1;
#pragma unroll
    for (int off = 16; off > 0; off >>= 1) {  // reduce 32 channel-pair lanes
      ps1 += __shfl_xor(ps1, off, 64);
      ps2 += __shfl_xor(ps2, off, 64);
    }
    float inv1 = 1.f / fmaxf(sqrtf(ps1), 1e-12f);
    float inv2 = 1.f / fmaxf(sqrtf(ps2), 1e-12f);
    if (half == 0) {
      int fr = __builtin_amdgcn_readfirstlane(fids[node]);
      float2 e2 = *(const float2*)(emb + (size_t)fr * DD + 2 * c);
      *(float2*)(outp + node * 192 + 2 * c) = e2;
      *(float2*)(outp + node * 192 + 64 + 2 * c) = make_float2(v1.x * inv1, v1.y * inv1);
      *(float2*)(outp + node * 192 + 128 + 2 * c) = make_float2(hv0 * inv2, hv1 * inv2);
    }
  }
}

// -------------------- launch --------------------

extern "C" void kernel_launch(void* const* d_in, const int* in_sizes, int n_in,
                              void* d_out, int out_size, void* d_ws, size_t ws_size,
                              hipStream_t stream) {
  const int* node_ids = (const int*)d_in[0];
  const int* src = (const int*)d_in[1];
  const int* dst = (const int*)d_in[2];
  const float* emb = (const float*)d_in[3];
  const float* W0 = (const float*)d_in[4];
  const float* b0 = (const float*)d_in[5];
  const float* W1 = (const float*)d_in[8];
  const float* b1 = (const float*)d_in[9];
  float* out = (float*)d_out;

  size_t o = 0;
  auto alloc = [&](size_t nbytes) {
    char* p = (char*)d_ws + o;
    o += (nbytes + 255) & ~(size_t)255;
    return (void*)p;
  };
  float* h1 = (float*)alloc((size_t)NN * DD * 4);
  unsigned* hfb = (unsigned*)alloc((size_t)NN * DD * 4);
  int* deg = (int*)alloc((size_t)N4 * 16);
  int* rp = (int*)alloc((size_t)(NN + 1) * 4);
  int* ssrc = (int*)alloc((size_t)NE * 4);
  int* pos = (int*)alloc((size_t)NE * 4);
  (void)o; (void)ws_size; (void)in_sizes; (void)n_in; (void)out_size;

  // layer-1 FC (independent of CSR) fused with deg zeroing in its tail blocks
  k_fc_mfma<<<FC_BLOCKS + ZB, 256, 0, stream>>>(emb, node_ids, W0, b0, hfb,
                                                (int4*)deg, N4);
  k_hist<<<(NE / 4 + 255) / 256, 256, 0, stream>>>((const int4*)dst, deg, (int4*)pos);
  int NB = (NN + 1023) / 1024;  // 49
  k_scan<<<NB, 1024, 0, stream>>>(deg, rp);
  k_scatter<<<(NE / 4 + 255) / 256, 256, 0, stream>>>(
      (const int4*)src, (const int4*)dst, rp, (const int4*)pos, ssrc);

  // layer 1 aggregation
  k_edge_t<false><<<(NN + 3) / 4, 256, 0, stream>>>(
      hfb, emb, node_ids, rp, ssrc, h1, DD, nullptr, nullptr, nullptr);
  // layer 2 FC
  k_fc_mfma<<<FC_BLOCKS, 256, 0, stream>>>(h1, nullptr, W1, b1, hfb, nullptr, 0);
  // layer 2 aggregation + fused finalize (norm h2, norm h1, copy h0)
  k_edge_t<true><<<(NN + 3) / 4, 256, 0, stream>>>(
      hfb, h1, nullptr, rp, ssrc, out, 0, emb, node_ids, h1);
}

// Round 11
// 164.815 us; speedup vs baseline: 1.0274x; 1.0274x over previous
//
#include <hip/hip_runtime.h>
#include <math.h>

#define NN 50000
#define NE 800000
#define DD 64
#define FC_BLOCKS 782  // ceil(NN/64)
#define N4 12503       // int4s of deg zeroed
#define ZB 49          // ceil(N4/256) zero blocks appended to fc1 grid

typedef __attribute__((ext_vector_type(8))) short short8v;
typedef __attribute__((ext_vector_type(4))) float floatx4;

__device__ __forceinline__ unsigned bf16r(float x) {  // round-to-nearest-even bf16
  unsigned u = __float_as_uint(x);
  return (u + 0x7fffu + ((u >> 16) & 1u)) >> 16;
}

// -------------------- kernels --------------------

// histogram dst degrees, 4 edges/thread, capturing per-edge position
__global__ void k_hist(const int4* __restrict__ dst4, int* __restrict__ deg,
                       int4* __restrict__ pos4) {
  int q = blockIdx.x * 256 + threadIdx.x;
  if (q >= NE / 4) return;
  int4 dn = dst4[q];
  int4 p;
  p.x = atomicAdd(&deg[dn.x], 1);
  p.y = atomicAdd(&deg[dn.y], 1);
  p.z = atomicAdd(&deg[dn.z], 1);
  p.w = atomicAdd(&deg[dn.w], 1);
  pos4[q] = p;
}

// single-kernel exclusive scan: each block redundantly pre-reduces its base
// (sum deg[0..blockStart), <=48 ints/thread), then local shuffle-scan.
__global__ void k_scan(const int* __restrict__ deg, int* __restrict__ rp) {
  __shared__ int wred[16];
  __shared__ int woff[16];
  __shared__ int sbase;
  int t = threadIdx.x;
  int lane = t & 63, w = t >> 6;
  int blockStart = blockIdx.x << 10;
  int acc = 0;
  for (int i = t; i < blockStart; i += 1024) acc += deg[i];
#pragma unroll
  for (int off = 32; off > 0; off >>= 1) acc += __shfl_xor(acc, off, 64);
  if (lane == 0) wred[w] = acc;
  __syncthreads();
  if (t == 0) {
    int b = 0;
#pragma unroll
    for (int k = 0; k < 16; ++k) b += wred[k];
    sbase = b;
  }
  int i = blockStart + t;
  int v = (i < NN) ? deg[i] : 0;
  int sc = v;  // inclusive within wave
#pragma unroll
  for (int off = 1; off < 64; off <<= 1) {
    int x = __shfl_up(sc, off, 64);
    if (lane >= off) sc += x;
  }
  if (lane == 63) woff[w] = sc;
  __syncthreads();
  if (t < 16) {
    int ws = woff[t];
    int s2 = ws;
#pragma unroll
    for (int off = 1; off < 16; off <<= 1) {
      int x = __shfl_up(s2, off, 64);
      if (t >= off) s2 += x;
    }
    woff[t] = s2 - ws;  // exclusive wave offset
  }
  __syncthreads();
  if (i <= NN) rp[i] = sc - v + woff[w] + sbase;  // rp[NN] lands as NE
}

// atomic-free scatter, 4 edges/thread
__global__ void k_scatter(const int4* __restrict__ src4, const int4* __restrict__ dst4,
                          const int* __restrict__ rp, const int4* __restrict__ pos4,
                          int* __restrict__ ssrc) {
  int q = blockIdx.x * 256 + threadIdx.x;
  if (q >= NE / 4) return;
  int4 s = src4[q], dn = dst4[q], p = pos4[q];
  ssrc[rp[dn.x] + p.x] = s.x;
  ssrc[rp[dn.y] + p.y] = s.y;
  ssrc[rp[dn.z] + p.z] = s.z;
  ssrc[rp[dn.w] + p.w] = s.w;
}

// MFMA FC (+ optional deg-zero blocks appended to the grid for layer 1)
__global__ void __launch_bounds__(256) k_fc_mfma(const float* __restrict__ h,
                                                 const int* __restrict__ ids,
                                                 const float* __restrict__ W,
                                                 const float* __restrict__ b,
                                                 unsigned* __restrict__ hfb,
                                                 int4* __restrict__ zbuf, int n4) {
  if (blockIdx.x >= FC_BLOCKS) {  // zero-deg tail blocks (layer 1 only)
    int i = (blockIdx.x - FC_BLOCKS) * 256 + threadIdx.x;
    if (i < n4) zbuf[i] = make_int4(0, 0, 0, 0);
    return;
  }
  int lane = threadIdx.x & 63;
  int wid = threadIdx.x >> 6;
  int nbase = blockIdx.x * 64 + wid * 16;
  if (nbase >= NN) return;
  int r16 = lane & 15, kg = lane >> 4;

  int rowA = ids ? ids[nbase + r16] : (nbase + r16);
  const float* hrow = h + (size_t)rowA * DD;
  short8v afr[2];
#pragma unroll
  for (int kt = 0; kt < 2; ++kt) {
    int k0 = kt * 32 + kg * 8;
#pragma unroll
    for (int i = 0; i < 8; ++i) afr[kt][i] = (short)bf16r(hrow[k0 + i]);
  }
  int orow[4];
#pragma unroll
  for (int r = 0; r < 4; ++r) {
    int node = nbase + kg * 4 + r;
    orow[r] = ids ? ids[node] : node;
  }
  short8v bfr[4][2];
#pragma unroll
  for (int dt = 0; dt < 4; ++dt) {
    const float* wrow = W + (dt * 16 + r16) * 64;
#pragma unroll
    for (int kt = 0; kt < 2; ++kt) {
      int k0 = kt * 32 + kg * 8;
#pragma unroll
      for (int i = 0; i < 8; ++i) bfr[dt][kt][i] = (short)bf16r(wrow[k0 + i]);
    }
  }
#pragma unroll
  for (int dt = 0; dt < 4; ++dt) {
    floatx4 acc = {0.f, 0.f, 0.f, 0.f};
    acc = __builtin_amdgcn_mfma_f32_16x16x32_bf16(afr[0], bfr[dt][0], acc, 0, 0, 0);
    acc = __builtin_amdgcn_mfma_f32_16x16x32_bf16(afr[1], bfr[dt][1], acc, 0, 0, 0);
    int d = dt * 16 + r16;
    float bias = b[d];
#pragma unroll
    for (int r = 0; r < 4; ++r) {
      int node = nbase + kg * 4 + r;
      float feat = fmaxf(acc[r] + bias, 0.f);
      float hv = h[(size_t)orow[r] * DD + d];
      hfb[node * DD + d] = bf16r(hv) | (bf16r(feat) << 16);
    }
  }
}

// One wave per dst node (R8 structure). Wave-uniform work on SALU via
// readfirstlane; softmax w/o max-subtraction (|e| bounded). Double-buffered
// 8-wide batches: next batch's ssrc+gather loads issue while current batch
// computes. Dup slots (clamped to lim) corrected using the final batch's
// slot-7 values (slot 7 of the last batch is always the lim row when rem>0).
template <bool FINAL>
__global__ void __launch_bounds__(256)
k_edge_t(const unsigned* __restrict__ hfb, const float* __restrict__ h,
         const int* __restrict__ ids, const int* __restrict__ rp,
         const int* __restrict__ ssrc, float* __restrict__ outp, int ostride,
         const float* __restrict__ emb, const int* __restrict__ fids,
         const float* __restrict__ h1) {
  int d = threadIdx.x & 63;
  int node = __builtin_amdgcn_readfirstlane(blockIdx.x * 4 + (threadIdx.x >> 6));
  int beg = __builtin_amdgcn_readfirstlane(rp[node]);
  int end = __builtin_amdgcn_readfirstlane(rp[node + 1]);
  int hrow = ids ? __builtin_amdgcn_readfirstlane(ids[node]) : node;
  float hd = h[(size_t)hrow * DD + d] * 1.44269504f;  // exp(x)=exp2(x*log2e)
  const unsigned* hfb_d = hfb + d;
  int deg = end - beg;
  int lim = end - 1;
  float ss = 0.f, aa = 0.f;
  if (deg > 0) {
    float s[8] = {0.f, 0.f, 0.f, 0.f, 0.f, 0.f, 0.f, 0.f};
    float a[8] = {0.f, 0.f, 0.f, 0.f, 0.f, 0.f, 0.f, 0.f};
    unsigned v[8];
#pragma unroll
    for (int j = 0; j < 8; ++j) {
      int q = beg + j;
      q = (q > lim) ? lim : q;  // SALU clamp
      v[j] = hfb_d[(size_t)__builtin_amdgcn_readfirstlane(ssrc[q]) * DD];
    }
    for (int p = beg + 8; p < end; p += 8) {
      unsigned w[8];
#pragma unroll
      for (int j = 0; j < 8; ++j) {  // issue next batch's loads first
        int q = p + j;
        q = (q > lim) ? lim : q;
        w[j] = hfb_d[(size_t)__builtin_amdgcn_readfirstlane(ssrc[q]) * DD];
      }
#pragma unroll
      for (int j = 0; j < 8; ++j) {  // compute current batch
        float hv = __uint_as_float(v[j] << 16);
        float fv = __uint_as_float(v[j] & 0xffff0000u);
        float ex = __builtin_amdgcn_exp2f(hv * hd);
        s[j] += ex;
        a[j] = fmaf(fv, ex, a[j]);
      }
#pragma unroll
      for (int j = 0; j < 8; ++j) v[j] = w[j];
    }
    float e7 = 0.f, f7 = 0.f;
#pragma unroll
    for (int j = 0; j < 8; ++j) {  // final batch
      float hv = __uint_as_float(v[j] << 16);
      float fv = __uint_as_float(v[j] & 0xffff0000u);
      float ex = __builtin_amdgcn_exp2f(hv * hd);
      s[j] += ex;
      a[j] = fmaf(fv, ex, a[j]);
      if (j == 7) { e7 = ex; f7 = fv; }
    }
    ss = ((s[0] + s[1]) + (s[2] + s[3])) + ((s[4] + s[5]) + (s[6] + s[7]));
    aa = ((a[0] + a[1]) + (a[2] + a[3])) + ((a[4] + a[5]) + (a[6] + a[7]));
    int dups = (8 - (deg & 7)) & 7;
    if (dups) {  // uniform branch; slot-7 of last batch was the lim row
      float fd = (float)dups;
      ss = fmaf(-fd, e7, ss);
      aa = fmaf(-fd * f7, e7, aa);
    }
  }
  float hval = (deg > 0) ? aa / ss : 0.f;
  if (!FINAL) {
    outp[(size_t)node * ostride + d] = hval;
  } else {
    float v1 = h1[(size_t)node * DD + d];
    float s1 = v1 * v1, s2 = hval * hval;
#pragma unroll
    for (int off = 32; off > 0; off >>= 1) {
      s1 += __shfl_xor(s1, off, 64);
      s2 += __shfl_xor(s2, off, 64);
    }
    outp[node * 192 + d] = emb[(size_t)fids[node] * DD + d];
    outp[node * 192 + 64 + d] = v1 / fmaxf(sqrtf(s1), 1e-12f);
    outp[node * 192 + 128 + d] = hval / fmaxf(sqrtf(s2), 1e-12f);
  }
}

// -------------------- launch --------------------

extern "C" void kernel_launch(void* const* d_in, const int* in_sizes, int n_in,
                              void* d_out, int out_size, void* d_ws, size_t ws_size,
                              hipStream_t stream) {
  const int* node_ids = (const int*)d_in[0];
  const int* src = (const int*)d_in[1];
  const int* dst = (const int*)d_in[2];
  const float* emb = (const float*)d_in[3];
  const float* W0 = (const float*)d_in[4];
  const float* b0 = (const float*)d_in[5];
  const float* W1 = (const float*)d_in[8];
  const float* b1 = (const float*)d_in[9];
  float* out = (float*)d_out;

  size_t o = 0;
  auto alloc = [&](size_t nbytes) {
    char* p = (char*)d_ws + o;
    o += (nbytes + 255) & ~(size_t)255;
    return (void*)p;
  };
  float* h1 = (float*)alloc((size_t)NN * DD * 4);
  unsigned* hfb = (unsigned*)alloc((size_t)NN * DD * 4);
  int* deg = (int*)alloc((size_t)N4 * 16);
  int* rp = (int*)alloc((size_t)(NN + 1) * 4);
  int* ssrc = (int*)alloc((size_t)NE * 4);
  int* pos = (int*)alloc((size_t)NE * 4);
  (void)o; (void)ws_size; (void)in_sizes; (void)n_in; (void)out_size;

  // layer-1 FC (independent of CSR) fused with deg zeroing in its tail blocks
  k_fc_mfma<<<FC_BLOCKS + ZB, 256, 0, stream>>>(emb, node_ids, W0, b0, hfb,
                                                (int4*)deg, N4);
  k_hist<<<(NE / 4 + 255) / 256, 256, 0, stream>>>((const int4*)dst, deg, (int4*)pos);
  int NB = (NN + 1023) / 1024;  // 49
  k_scan<<<NB, 1024, 0, stream>>>(deg, rp);
  k_scatter<<<(NE / 4 + 255) / 256, 256, 0, stream>>>(
      (const int4*)src, (const int4*)dst, rp, (const int4*)pos, ssrc);

  // layer 1 aggregation
  k_edge_t<false><<<(NN + 3) / 4, 256, 0, stream>>>(
      hfb, emb, node_ids, rp, ssrc, h1, DD, nullptr, nullptr, nullptr);
  // layer 2 FC
  k_fc_mfma<<<FC_BLOCKS, 256, 0, stream>>>(h1, nullptr, W1, b1, hfb, nullptr, 0);
  // layer 2 aggregation + fused finalize (norm h2, norm h1, copy h0)
  k_edge_t<true><<<(NN + 3) / 4, 256, 0, stream>>>(
      hfb, h1, nullptr, rp, ssrc, out, 0, emb, node_ids, h1);
}

// Round 12
// 163.740 us; speedup vs baseline: 1.0341x; 1.0066x over previous
//
#include <hip/hip_runtime.h>
#include <math.h>

#define NN 50000
#define NE 800000
#define DD 64
#define FC_BLOCKS 782  // ceil(NN/64)
#define N4 12503       // int4s of deg zeroed
#define ZB 49          // ceil(N4/256) zero blocks appended to fc1 grid

typedef __attribute__((ext_vector_type(8))) short short8v;
typedef __attribute__((ext_vector_type(4))) float floatx4;

__device__ __forceinline__ unsigned bf16r(float x) {  // round-to-nearest-even bf16
  unsigned u = __float_as_uint(x);
  return (u + 0x7fffu + ((u >> 16) & 1u)) >> 16;
}

// -------------------- kernels --------------------

// histogram dst degrees, 4 edges/thread, capturing per-edge position
__global__ void k_hist(const int4* __restrict__ dst4, int* __restrict__ deg,
                       int4* __restrict__ pos4) {
  int q = blockIdx.x * 256 + threadIdx.x;
  if (q >= NE / 4) return;
  int4 dn = dst4[q];
  int4 p;
  p.x = atomicAdd(&deg[dn.x], 1);
  p.y = atomicAdd(&deg[dn.y], 1);
  p.z = atomicAdd(&deg[dn.z], 1);
  p.w = atomicAdd(&deg[dn.w], 1);
  pos4[q] = p;
}

// single-kernel exclusive scan: each block redundantly pre-reduces its base
// (sum deg[0..blockStart)), then local shuffle-scan.
__global__ void k_scan(const int* __restrict__ deg, int* __restrict__ rp) {
  __shared__ int wred[16];
  __shared__ int woff[16];
  __shared__ int sbase;
  int t = threadIdx.x;
  int lane = t & 63, w = t >> 6;
  int blockStart = blockIdx.x << 10;
  int acc = 0;
  for (int i = t; i < blockStart; i += 1024) acc += deg[i];
#pragma unroll
  for (int off = 32; off > 0; off >>= 1) acc += __shfl_xor(acc, off, 64);
  if (lane == 0) wred[w] = acc;
  __syncthreads();
  if (t == 0) {
    int b = 0;
#pragma unroll
    for (int k = 0; k < 16; ++k) b += wred[k];
    sbase = b;
  }
  int i = blockStart + t;
  int v = (i < NN) ? deg[i] : 0;
  int sc = v;  // inclusive within wave
#pragma unroll
  for (int off = 1; off < 64; off <<= 1) {
    int x = __shfl_up(sc, off, 64);
    if (lane >= off) sc += x;
  }
  if (lane == 63) woff[w] = sc;
  __syncthreads();
  if (t < 16) {
    int ws = woff[t];
    int s2 = ws;
#pragma unroll
    for (int off = 1; off < 16; off <<= 1) {
      int x = __shfl_up(s2, off, 64);
      if (t >= off) s2 += x;
    }
    woff[t] = s2 - ws;  // exclusive wave offset
  }
  __syncthreads();
  if (i <= NN) rp[i] = sc - v + woff[w] + sbase;  // rp[NN] lands as NE
}

// atomic-free scatter, 4 edges/thread
__global__ void k_scatter(const int4* __restrict__ src4, const int4* __restrict__ dst4,
                          const int* __restrict__ rp, const int4* __restrict__ pos4,
                          int* __restrict__ ssrc) {
  int q = blockIdx.x * 256 + threadIdx.x;
  if (q >= NE / 4) return;
  int4 s = src4[q], dn = dst4[q], p = pos4[q];
  ssrc[rp[dn.x] + p.x] = s.x;
  ssrc[rp[dn.y] + p.y] = s.y;
  ssrc[rp[dn.z] + p.z] = s.z;
  ssrc[rp[dn.w] + p.w] = s.w;
}

// MFMA FC (+ optional deg-zero blocks appended to the grid for layer 1)
__global__ void __launch_bounds__(256) k_fc_mfma(const float* __restrict__ h,
                                                 const int* __restrict__ ids,
                                                 const float* __restrict__ W,
                                                 const float* __restrict__ b,
                                                 unsigned* __restrict__ hfb,
                                                 int4* __restrict__ zbuf, int n4) {
  if (blockIdx.x >= FC_BLOCKS) {  // zero-deg tail blocks (layer 1 only)
    int i = (blockIdx.x - FC_BLOCKS) * 256 + threadIdx.x;
    if (i < n4) zbuf[i] = make_int4(0, 0, 0, 0);
    return;
  }
  int lane = threadIdx.x & 63;
  int wid = threadIdx.x >> 6;
  int nbase = blockIdx.x * 64 + wid * 16;
  if (nbase >= NN) return;
  int r16 = lane & 15, kg = lane >> 4;

  int rowA = ids ? ids[nbase + r16] : (nbase + r16);
  const float* hrow = h + (size_t)rowA * DD;
  short8v afr[2];
#pragma unroll
  for (int kt = 0; kt < 2; ++kt) {
    int k0 = kt * 32 + kg * 8;
#pragma unroll
    for (int i = 0; i < 8; ++i) afr[kt][i] = (short)bf16r(hrow[k0 + i]);
  }
  int orow[4];
#pragma unroll
  for (int r = 0; r < 4; ++r) {
    int node = nbase + kg * 4 + r;
    orow[r] = ids ? ids[node] : node;
  }
  short8v bfr[4][2];
#pragma unroll
  for (int dt = 0; dt < 4; ++dt) {
    const float* wrow = W + (dt * 16 + r16) * 64;
#pragma unroll
    for (int kt = 0; kt < 2; ++kt) {
      int k0 = kt * 32 + kg * 8;
#pragma unroll
      for (int i = 0; i < 8; ++i) bfr[dt][kt][i] = (short)bf16r(wrow[k0 + i]);
    }
  }
#pragma unroll
  for (int dt = 0; dt < 4; ++dt) {
    floatx4 acc = {0.f, 0.f, 0.f, 0.f};
    acc = __builtin_amdgcn_mfma_f32_16x16x32_bf16(afr[0], bfr[dt][0], acc, 0, 0, 0);
    acc = __builtin_amdgcn_mfma_f32_16x16x32_bf16(afr[1], bfr[dt][1], acc, 0, 0, 0);
    int d = dt * 16 + r16;
    float bias = b[d];
#pragma unroll
    for (int r = 0; r < 4; ++r) {
      int node = nbase + kg * 4 + r;
      float feat = fmaxf(acc[r] + bias, 0.f);
      float hv = h[(size_t)orow[r] * DD + d];
      hfb[node * DD + d] = bf16r(hv) | (bf16r(feat) << 16);
    }
  }
}

// One wave per dst node. Edge indices fetched 64-at-a-time with ONE coalesced
// vector load; per-slot index extracted with v_readlane (VALU, ~4cy) into
// SGPR -> gather chain has no scalar-memory wait. Double-buffered 8-wide
// batches; clamped dup slots corrected via last batch's slot-7 values.
// Softmax w/o max-subtraction (|e| bounded).
template <bool FINAL>
__global__ void __launch_bounds__(256)
k_edge_t(const unsigned* __restrict__ hfb, const float* __restrict__ h,
         const int* __restrict__ ids, const int* __restrict__ rp,
         const int* __restrict__ ssrc, float* __restrict__ outp, int ostride,
         const float* __restrict__ emb, const int* __restrict__ fids,
         const float* __restrict__ h1) {
  int lane = threadIdx.x & 63;
  int d = lane;
  int node = __builtin_amdgcn_readfirstlane(blockIdx.x * 4 + (threadIdx.x >> 6));
  int beg = __builtin_amdgcn_readfirstlane(rp[node]);
  int end = __builtin_amdgcn_readfirstlane(rp[node + 1]);
  int hrow = ids ? __builtin_amdgcn_readfirstlane(ids[node]) : node;
  float hd = h[(size_t)hrow * DD + d] * 1.44269504f;  // exp(x)=exp2(x*log2e)
  const unsigned* hfb_d = hfb + d;
  int deg = end - beg;
  int lim = end - 1;
  float ss = 0.f, aa = 0.f;
  if (deg > 0) {
    float s[8] = {0.f, 0.f, 0.f, 0.f, 0.f, 0.f, 0.f, 0.f};
    float a[8] = {0.f, 0.f, 0.f, 0.f, 0.f, 0.f, 0.f, 0.f};
    float e7 = 0.f, f7 = 0.f;
    for (int sb = beg; sb < end; sb += 64) {  // super-batch: 64 edge idx/load
      int e = sb + lane;
      e = (e > lim) ? lim : e;
      int vidx = ssrc[e];  // one coalesced load covers 64 edges
      int cnt = __builtin_amdgcn_readfirstlane(min(64, end - sb));
      int clim = cnt - 1;
      unsigned v[8];
#pragma unroll
      for (int j = 0; j < 8; ++j) {
        int sl = (j > clim) ? clim : j;  // SALU clamp
        int idx = __builtin_amdgcn_readlane(vidx, sl);
        v[j] = hfb_d[(size_t)idx * DD];
      }
      for (int p = 8; p < cnt; p += 8) {
        unsigned w[8];
#pragma unroll
        for (int j = 0; j < 8; ++j) {  // issue next batch's gathers first
          int sl = p + j;
          sl = (sl > clim) ? clim : sl;
          int idx = __builtin_amdgcn_readlane(vidx, sl);
          w[j] = hfb_d[(size_t)idx * DD];
        }
#pragma unroll
        for (int j = 0; j < 8; ++j) {  // compute current batch
          float hv = __uint_as_float(v[j] << 16);
          float fv = __uint_as_float(v[j] & 0xffff0000u);
          float ex = __builtin_amdgcn_exp2f(hv * hd);
          s[j] += ex;
          a[j] = fmaf(fv, ex, a[j]);
        }
#pragma unroll
        for (int j = 0; j < 8; ++j) v[j] = w[j];
      }
#pragma unroll
      for (int j = 0; j < 8; ++j) {  // final batch of super-batch
        float hv = __uint_as_float(v[j] << 16);
        float fv = __uint_as_float(v[j] & 0xffff0000u);
        float ex = __builtin_amdgcn_exp2f(hv * hd);
        s[j] += ex;
        a[j] = fmaf(fv, ex, a[j]);
        if (j == 7) { e7 = ex; f7 = fv; }
      }
    }
    ss = ((s[0] + s[1]) + (s[2] + s[3])) + ((s[4] + s[5]) + (s[6] + s[7]));
    aa = ((a[0] + a[1]) + (a[2] + a[3])) + ((a[4] + a[5]) + (a[6] + a[7]));
    int dups = (8 - (deg & 7)) & 7;
    if (dups) {  // uniform branch; slot-7 of the overall last batch = lim row
      float fd = (float)dups;
      ss = fmaf(-fd, e7, ss);
      aa = fmaf(-fd * f7, e7, aa);
    }
  }
  float hval = (deg > 0) ? aa / ss : 0.f;
  if (!FINAL) {
    outp[(size_t)node * ostride + d] = hval;
  } else {
    float v1 = h1[(size_t)node * DD + d];
    float s1 = v1 * v1, s2 = hval * hval;
#pragma unroll
    for (int off = 32; off > 0; off >>= 1) {
      s1 += __shfl_xor(s1, off, 64);
      s2 += __shfl_xor(s2, off, 64);
    }
    outp[node * 192 + d] = emb[(size_t)fids[node] * DD + d];
    outp[node * 192 + 64 + d] = v1 / fmaxf(sqrtf(s1), 1e-12f);
    outp[node * 192 + 128 + d] = hval / fmaxf(sqrtf(s2), 1e-12f);
  }
}

// -------------------- launch --------------------

extern "C" void kernel_launch(void* const* d_in, const int* in_sizes, int n_in,
                              void* d_out, int out_size, void* d_ws, size_t ws_size,
                              hipStream_t stream) {
  const int* node_ids = (const int*)d_in[0];
  const int* src = (const int*)d_in[1];
  const int* dst = (const int*)d_in[2];
  const float* emb = (const float*)d_in[3];
  const float* W0 = (const float*)d_in[4];
  const float* b0 = (const float*)d_in[5];
  const float* W1 = (const float*)d_in[8];
  const float* b1 = (const float*)d_in[9];
  float* out = (float*)d_out;

  size_t o = 0;
  auto alloc = [&](size_t nbytes) {
    char* p = (char*)d_ws + o;
    o += (nbytes + 255) & ~(size_t)255;
    return (void*)p;
  };
  float* h1 = (float*)alloc((size_t)NN * DD * 4);
  unsigned* hfb = (unsigned*)alloc((size_t)NN * DD * 4);
  int* deg = (int*)alloc((size_t)N4 * 16);
  int* rp = (int*)alloc((size_t)(NN + 1) * 4);
  int* ssrc = (int*)alloc((size_t)NE * 4);
  int* pos = (int*)alloc((size_t)NE * 4);
  (void)o; (void)ws_size; (void)in_sizes; (void)n_in; (void)out_size;

  // layer-1 FC (independent of CSR) fused with deg zeroing in its tail blocks
  k_fc_mfma<<<FC_BLOCKS + ZB, 256, 0, stream>>>(emb, node_ids, W0, b0, hfb,
                                                (int4*)deg, N4);
  k_hist<<<(NE / 4 + 255) / 256, 256, 0, stream>>>((const int4*)dst, deg, (int4*)pos);
  int NB = (NN + 1023) / 1024;  // 49
  k_scan<<<NB, 1024, 0, stream>>>(deg, rp);
  k_scatter<<<(NE / 4 + 255) / 256, 256, 0, stream>>>(
      (const int4*)src, (const int4*)dst, rp, (const int4*)pos, ssrc);

  // layer 1 aggregation
  k_edge_t<false><<<(NN + 3) / 4, 256, 0, stream>>>(
      hfb, emb, node_ids, rp, ssrc, h1, DD, nullptr, nullptr, nullptr);
  // layer 2 FC
  k_fc_mfma<<<FC_BLOCKS, 256, 0, stream>>>(h1, nullptr, W1, b1, hfb, nullptr, 0);
  // layer 2 aggregation + fused finalize (norm h2, norm h1, copy h0)
  k_edge_t<true><<<(NN + 3) / 4, 256, 0, stream>>>(
      hfb, h1, nullptr, rp, ssrc, out, 0, emb, node_ids, h1);
}

// Round 13
// 163.568 us; speedup vs baseline: 1.0352x; 1.0011x over previous
//
#include <hip/hip_runtime.h>
#include <math.h>

#define NN 50000
#define NE 800000
#define DD 64
#define FC_BLOCKS 782  // ceil(NN/64)
#define N4 12503       // int4s of deg zeroed
#define ZB 49          // ceil(N4/256) zero blocks appended to fc1 grid

typedef __attribute__((ext_vector_type(8))) short short8v;
typedef __attribute__((ext_vector_type(4))) float floatx4;
typedef unsigned short ushort;

__device__ __forceinline__ unsigned bf16r(float x) {  // round-to-nearest-even bf16
  unsigned u = __float_as_uint(x);
  return (u + 0x7fffu + ((u >> 16) & 1u)) >> 16;
}
__device__ __forceinline__ float b2f(ushort u) {
  return __uint_as_float((unsigned)u << 16);
}

// -------------------- kernels --------------------

// histogram dst degrees, 4 edges/thread, capturing per-edge position
__global__ void k_hist(const int4* __restrict__ dst4, int* __restrict__ deg,
                       int4* __restrict__ pos4) {
  int q = blockIdx.x * 256 + threadIdx.x;
  if (q >= NE / 4) return;
  int4 dn = dst4[q];
  int4 p;
  p.x = atomicAdd(&deg[dn.x], 1);
  p.y = atomicAdd(&deg[dn.y], 1);
  p.z = atomicAdd(&deg[dn.z], 1);
  p.w = atomicAdd(&deg[dn.w], 1);
  pos4[q] = p;
}

// single-kernel exclusive scan: each block redundantly pre-reduces its base
// (sum deg[0..blockStart)), then local shuffle-scan.
__global__ void k_scan(const int* __restrict__ deg, int* __restrict__ rp) {
  __shared__ int wred[16];
  __shared__ int woff[16];
  __shared__ int sbase;
  int t = threadIdx.x;
  int lane = t & 63, w = t >> 6;
  int blockStart = blockIdx.x << 10;
  int acc = 0;
  for (int i = t; i < blockStart; i += 1024) acc += deg[i];
#pragma unroll
  for (int off = 32; off > 0; off >>= 1) acc += __shfl_xor(acc, off, 64);
  if (lane == 0) wred[w] = acc;
  __syncthreads();
  if (t == 0) {
    int b = 0;
#pragma unroll
    for (int k = 0; k < 16; ++k) b += wred[k];
    sbase = b;
  }
  int i = blockStart + t;
  int v = (i < NN) ? deg[i] : 0;
  int sc = v;  // inclusive within wave
#pragma unroll
  for (int off = 1; off < 64; off <<= 1) {
    int x = __shfl_up(sc, off, 64);
    if (lane >= off) sc += x;
  }
  if (lane == 63) woff[w] = sc;
  __syncthreads();
  if (t < 16) {
    int ws = woff[t];
    int s2 = ws;
#pragma unroll
    for (int off = 1; off < 16; off <<= 1) {
      int x = __shfl_up(s2, off, 64);
      if (t >= off) s2 += x;
    }
    woff[t] = s2 - ws;  // exclusive wave offset
  }
  __syncthreads();
  if (i <= NN) rp[i] = sc - v + woff[w] + sbase;  // rp[NN] lands as NE
}

// atomic-free scatter, 4 edges/thread
__global__ void k_scatter(const int4* __restrict__ src4, const int4* __restrict__ dst4,
                          const int* __restrict__ rp, const int4* __restrict__ pos4,
                          int* __restrict__ ssrc) {
  int q = blockIdx.x * 256 + threadIdx.x;
  if (q >= NE / 4) return;
  int4 s = src4[q], dn = dst4[q], p = pos4[q];
  ssrc[rp[dn.x] + p.x] = s.x;
  ssrc[rp[dn.y] + p.y] = s.y;
  ssrc[rp[dn.z] + p.z] = s.z;
  ssrc[rp[dn.w] + p.w] = s.w;
}

// MFMA FC. HBF16: h is bf16 ushort rows (direct frag loads); else f32 + ids.
template <bool HBF16>
__global__ void __launch_bounds__(256) k_fc_mfma(const void* __restrict__ hp,
                                                 const int* __restrict__ ids,
                                                 const float* __restrict__ W,
                                                 const float* __restrict__ b,
                                                 unsigned* __restrict__ hfb,
                                                 int4* __restrict__ zbuf, int n4) {
  if (blockIdx.x >= FC_BLOCKS) {  // zero-deg tail blocks (layer 1 only)
    int i = (blockIdx.x - FC_BLOCKS) * 256 + threadIdx.x;
    if (i < n4) zbuf[i] = make_int4(0, 0, 0, 0);
    return;
  }
  int lane = threadIdx.x & 63;
  int wid = threadIdx.x >> 6;
  int nbase = blockIdx.x * 64 + wid * 16;
  if (nbase >= NN) return;
  int r16 = lane & 15, kg = lane >> 4;

  int rowA = (!HBF16 && ids) ? ids[nbase + r16] : (nbase + r16);
  short8v afr[2];
  if (HBF16) {
    const ushort* hrow = (const ushort*)hp + (size_t)rowA * DD;
#pragma unroll
    for (int kt = 0; kt < 2; ++kt)
      afr[kt] = *(const short8v*)(hrow + kt * 32 + kg * 8);
  } else {
    const float* hrow = (const float*)hp + (size_t)rowA * DD;
#pragma unroll
    for (int kt = 0; kt < 2; ++kt) {
      int k0 = kt * 32 + kg * 8;
#pragma unroll
      for (int i = 0; i < 8; ++i) afr[kt][i] = (short)bf16r(hrow[k0 + i]);
    }
  }
  int orow[4];
#pragma unroll
  for (int r = 0; r < 4; ++r) {
    int node = nbase + kg * 4 + r;
    orow[r] = (!HBF16 && ids) ? ids[node] : node;
  }
  short8v bfr[4][2];
#pragma unroll
  for (int dt = 0; dt < 4; ++dt) {
    const float* wrow = W + (dt * 16 + r16) * 64;
#pragma unroll
    for (int kt = 0; kt < 2; ++kt) {
      int k0 = kt * 32 + kg * 8;
#pragma unroll
      for (int i = 0; i < 8; ++i) bfr[dt][kt][i] = (short)bf16r(wrow[k0 + i]);
    }
  }
#pragma unroll
  for (int dt = 0; dt < 4; ++dt) {
    floatx4 acc = {0.f, 0.f, 0.f, 0.f};
    acc = __builtin_amdgcn_mfma_f32_16x16x32_bf16(afr[0], bfr[dt][0], acc, 0, 0, 0);
    acc = __builtin_amdgcn_mfma_f32_16x16x32_bf16(afr[1], bfr[dt][1], acc, 0, 0, 0);
    int d = dt * 16 + r16;
    float bias = b[d];
#pragma unroll
    for (int r = 0; r < 4; ++r) {
      int node = nbase + kg * 4 + r;
      float feat = fmaxf(acc[r] + bias, 0.f);
      unsigned lo = HBF16 ? (unsigned)((const ushort*)hp)[(size_t)orow[r] * DD + d]
                          : bf16r(((const float*)hp)[(size_t)orow[r] * DD + d]);
      hfb[node * DD + d] = lo | (bf16r(feat) << 16);
    }
  }
}

// One wave per dst node (R9-proven structure). Wave-uniform work on SALU via
// readfirstlane; softmax w/o max-subtraction (|e| bounded). 8-wide batches;
// clamped dup slots corrected with the last batch's slot-7 values (free).
// FINAL fuses l2-normalize(h2), l2-normalize(h1), h0 copy.
template <bool FINAL, bool HBF16>
__global__ void __launch_bounds__(256)
k_edge_t(const unsigned* __restrict__ hfb, const void* __restrict__ hp,
         const int* __restrict__ ids, const int* __restrict__ rp,
         const int* __restrict__ ssrc, void* __restrict__ outp,
         const float* __restrict__ emb, const int* __restrict__ fids,
         const ushort* __restrict__ h1b) {
  int d = threadIdx.x & 63;
  int node = __builtin_amdgcn_readfirstlane(blockIdx.x * 4 + (threadIdx.x >> 6));
  int beg = __builtin_amdgcn_readfirstlane(rp[node]);
  int end = __builtin_amdgcn_readfirstlane(rp[node + 1]);
  int hrow = (!HBF16 && ids) ? __builtin_amdgcn_readfirstlane(ids[node]) : node;
  float hdr = HBF16 ? b2f(((const ushort*)hp)[(size_t)hrow * DD + d])
                    : ((const float*)hp)[(size_t)hrow * DD + d];
  float hd = hdr * 1.44269504f;  // exp(x)=exp2(x*log2e)
  const unsigned* hfb_d = hfb + d;
  int deg = end - beg;
  int lim = end - 1;
  float ss = 0.f, aa = 0.f;
  if (deg > 0) {
    float s[8] = {0.f, 0.f, 0.f, 0.f, 0.f, 0.f, 0.f, 0.f};
    float a[8] = {0.f, 0.f, 0.f, 0.f, 0.f, 0.f, 0.f, 0.f};
    float e7 = 0.f, f7 = 0.f;
    for (int p = beg; p < end; p += 8) {
      unsigned v[8];
#pragma unroll
      for (int j = 0; j < 8; ++j) {
        int q = p + j;
        q = (q > lim) ? lim : q;  // SALU clamp
        v[j] = hfb_d[(size_t)__builtin_amdgcn_readfirstlane(ssrc[q]) * DD];
      }
#pragma unroll
      for (int j = 0; j < 8; ++j) {
        float hv = __uint_as_float(v[j] << 16);
        float fv = __uint_as_float(v[j] & 0xffff0000u);
        float ex = __builtin_amdgcn_exp2f(hv * hd);
        s[j] += ex;
        a[j] = fmaf(fv, ex, a[j]);
        if (j == 7) { e7 = ex; f7 = fv; }  // last batch's values survive
      }
    }
    ss = ((s[0] + s[1]) + (s[2] + s[3])) + ((s[4] + s[5]) + (s[6] + s[7]));
    aa = ((a[0] + a[1]) + (a[2] + a[3])) + ((a[4] + a[5]) + (a[6] + a[7]));
    int dups = (8 - (deg & 7)) & 7;
    if (dups) {  // uniform branch; slot-7 of last batch was the lim row
      float fd = (float)dups;
      ss = fmaf(-fd, e7, ss);
      aa = fmaf(-fd * f7, e7, aa);
    }
  }
  float hval = (deg > 0) ? aa / ss : 0.f;
  if (!FINAL) {
    ((ushort*)outp)[(size_t)node * DD + d] = (ushort)bf16r(hval);  // h1 as bf16
  } else {
    float* out = (float*)outp;
    float v1 = b2f(h1b[(size_t)node * DD + d]);
    float s1 = v1 * v1, s2 = hval * hval;
#pragma unroll
    for (int off = 32; off > 0; off >>= 1) {
      s1 += __shfl_xor(s1, off, 64);
      s2 += __shfl_xor(s2, off, 64);
    }
    out[node * 192 + d] = emb[(size_t)fids[node] * DD + d];
    out[node * 192 + 64 + d] = v1 / fmaxf(sqrtf(s1), 1e-12f);
    out[node * 192 + 128 + d] = hval / fmaxf(sqrtf(s2), 1e-12f);
  }
}

// -------------------- launch --------------------

extern "C" void kernel_launch(void* const* d_in, const int* in_sizes, int n_in,
                              void* d_out, int out_size, void* d_ws, size_t ws_size,
                              hipStream_t stream) {
  const int* node_ids = (const int*)d_in[0];
  const int* src = (const int*)d_in[1];
  const int* dst = (const int*)d_in[2];
  const float* emb = (const float*)d_in[3];
  const float* W0 = (const float*)d_in[4];
  const float* b0 = (const float*)d_in[5];
  const float* W1 = (const float*)d_in[8];
  const float* b1 = (const float*)d_in[9];
  float* out = (float*)d_out;

  size_t o = 0;
  auto alloc = [&](size_t nbytes) {
    char* p = (char*)d_ws + o;
    o += (nbytes + 255) & ~(size_t)255;
    return (void*)p;
  };
  ushort* h1b = (ushort*)alloc((size_t)NN * DD * 2);  // h1 stored as bf16
  unsigned* hfb = (unsigned*)alloc((size_t)NN * DD * 4);
  int* deg = (int*)alloc((size_t)N4 * 16);
  int* rp = (int*)alloc((size_t)(NN + 1) * 4);
  int* ssrc = (int*)alloc((size_t)NE * 4);
  int* pos = (int*)alloc((size_t)NE * 4);
  (void)o; (void)ws_size; (void)in_sizes; (void)n_in; (void)out_size;

  // layer-1 FC (independent of CSR) fused with deg zeroing in its tail blocks
  k_fc_mfma<false><<<FC_BLOCKS + ZB, 256, 0, stream>>>(emb, node_ids, W0, b0, hfb,
                                                       (int4*)deg, N4);
  k_hist<<<(NE / 4 + 255) / 256, 256, 0, stream>>>((const int4*)dst, deg, (int4*)pos);
  int NB = (NN + 1023) / 1024;  // 49
  k_scan<<<NB, 1024, 0, stream>>>(deg, rp);
  k_scatter<<<(NE / 4 + 255) / 256, 256, 0, stream>>>(
      (const int4*)src, (const int4*)dst, rp, (const int4*)pos, ssrc);

  // layer 1 aggregation -> h1 (bf16)
  k_edge_t<false, false><<<(NN + 3) / 4, 256, 0, stream>>>(
      hfb, emb, node_ids, rp, ssrc, h1b, nullptr, nullptr, nullptr);
  // layer 2 FC (bf16 input, direct frag loads)
  k_fc_mfma<true><<<FC_BLOCKS, 256, 0, stream>>>(h1b, nullptr, W1, b1, hfb,
                                                 nullptr, 0);
  // layer 2 aggregation + fused finalize (norm h2, norm h1, copy h0)
  k_edge_t<true, true><<<(NN + 3) / 4, 256, 0, stream>>>(
      hfb, h1b, nullptr, rp, ssrc, out, emb, node_ids, h1b);
}